// Round 9
// baseline (865.350 us; speedup 1.0000x reference)
//
#include <hip/hip_runtime.h>
#include <hip/hip_bf16.h>

// ---------------------------------------------------------------------------
// GCN: h = relu(gcnconv(x,W1,b1)); z = gcnconv(h,W2,b2); out[e]=dot(z[s],z[d])
// Counting sort partitions edges by 256-node bucket (hist -> rowscan ->
// reorder), keeping all random writes in block-owned full-line runs.
// NO CSR: aggregation is edge-parallel per 64-node slice with fp32 LDS
// accumulators (ds_add_f32), seeded by the self-loop row; epilogue applies
// dis/bias/relu and packs. bucket_deg computes dis (degree) from part.
// GEMM epilogue pre-scales rows by dis and packs to BF16 (128B/row tables).
// (R5 lesson kept: no __shfl across group-divergent tails.)
// ---------------------------------------------------------------------------

constexpr int NC = 512;      // edge chunks (= hist/reorder grid)
constexpr int NBPAD = 256;   // padded bucket count (>= 196 actual)
constexpr int BSHIFT = 8;    // 256 nodes per sort bucket (64B reorder runs)

__device__ __forceinline__ unsigned short f2bf(float f) {   // RNE
    unsigned u = __float_as_uint(f);
    return (unsigned short)((u + 0x7FFF + ((u >> 16) & 1)) >> 16);
}
__device__ __forceinline__ float bflo(unsigned u) { return __uint_as_float(u << 16); }
__device__ __forceinline__ float bfhi(unsigned u) { return __uint_as_float(u & 0xFFFF0000u); }

// histCM[c*NBPAD+b] = count of bucket-b edges in chunk c (coalesced writes);
// bsums[b] = bucket totals via global atomics.
__global__ __launch_bounds__(256) void hist_kernel(const int* __restrict__ col,
                                                   int* __restrict__ histCM,
                                                   int* __restrict__ bsums, int E, int CE) {
    __shared__ int hl[NBPAD];
    const int t = threadIdx.x, c = blockIdx.x;
    hl[t] = 0;
    __syncthreads();
    const int s = c * CE, e = min(E, s + CE);
    for (int i = s + t; i < e; i += 256) atomicAdd(&hl[col[i] >> BSHIFT], 1);
    __syncthreads();
    const int v = hl[t];
    histCM[c * NBPAD + t] = v;
    if (v) atomicAdd(&bsums[t], v);
}

// Block b: bucket base = sum(bsums[k<b]) (masked reduce), then exclusive scan
// of the bucket's NC chunk counts (2/thread) -> offsBM[b*NC+c] (coalesced).
__global__ __launch_bounds__(256) void rowscan_kernel(const int* __restrict__ histCM,
                                                      const int* __restrict__ bsums,
                                                      int* __restrict__ offsBM) {
    __shared__ int red[256];
    __shared__ int sc[256];
    const int t = threadIdx.x, b = blockIdx.x;
    red[t] = (t < b) ? bsums[t] : 0;
    __syncthreads();
    for (int off = 128; off > 0; off >>= 1) {
        if (t < off) red[t] += red[t + off];
        __syncthreads();
    }
    const int base = red[0];
    const int a0 = histCM[(2 * t) * NBPAD + b];
    const int a1 = histCM[(2 * t + 1) * NBPAD + b];
    const int ps = a0 + a1;
    sc[t] = ps;
    __syncthreads();
    for (int off = 1; off < 256; off <<= 1) {
        int u = (t >= off) ? sc[t - off] : 0;
        __syncthreads();
        sc[t] += u;
        __syncthreads();
    }
    const int excl = sc[t] - ps;
    offsBM[b * NC + 2 * t] = base + excl;
    offsBM[b * NC + 2 * t + 1] = base + excl + a0;
}

// Scatter (row,col) pairs into per-(bucket,chunk) contiguous runs of part[].
__global__ __launch_bounds__(256) void reorder_kernel(const int* __restrict__ row,
                                                      const int* __restrict__ col,
                                                      const int* __restrict__ offsBM,
                                                      int2* __restrict__ part, int E, int CE) {
    __shared__ int cur[NBPAD];
    const int t = threadIdx.x, c = blockIdx.x;
    cur[t] = offsBM[t * NC + c];
    __syncthreads();
    const int s = c * CE, e = min(E, s + CE);
    for (int i = s + t; i < e; i += 256) {
        const int r = row[i], cl = col[i];
        const int p = atomicAdd(&cur[cl >> BSHIFT], 1);
        part[p] = make_int2(r, cl);
    }
}

// One block per bucket: per-node degree from part -> dis = rsqrt(deg+1).
__global__ __launch_bounds__(256) void bucket_deg_kernel(const int2* __restrict__ part,
                                                         const int* __restrict__ offsBM,
                                                         float* __restrict__ dis,
                                                         int N, int E) {
    __shared__ int cnt[256];
    const int t = threadIdx.x, b = blockIdx.x;
    const int base = b << BSHIFT;
    const int bstart = offsBM[b * NC];
    const int bend = (b + 1 < NBPAD) ? offsBM[(b + 1) * NC] : E;
    cnt[t] = 0;
    __syncthreads();
    for (int i = bstart + t; i < bend; i += 256) atomicAdd(&cnt[part[i].y - base], 1);
    __syncthreads();
    const int node = base + t;
    if (node < N) dis[node] = rsqrtf((float)(cnt[t] + 1));   // +1 = self loop
}

// Y[N,64] (bf16) = rowscale[r] * (X[N,K] @ W[K,64]).
// Block = 256 thr = 16x16 grid; 4x4 register micro-tile; both operands in
// LDS (k-major); per k: 2 ds_read_b128 + 16 FMAs, no global loads in k-loop.
template <int K>
__global__ __launch_bounds__(256) void gemm_tile(const float* __restrict__ X,
                                                 const float* __restrict__ W,
                                                 const float* __restrict__ rowscale,
                                                 unsigned short* __restrict__ Y, int nrows) {
    __shared__ float sX[64 * 64];
    __shared__ float sW[64 * 64];
    const int tid = threadIdx.x;
    const int tx = tid & 15;         // col group
    const int ty = tid >> 4;         // row group
    const int rowbase = blockIdx.x * 64;

    float acc[16];
    #pragma unroll
    for (int i = 0; i < 16; ++i) acc[i] = 0.f;

    const int lr = tid & 63;         // loader row (0..63)
    const int lq = tid >> 6;         // loader k-quarter (16 k's each)
    int grow = rowbase + lr;
    if (grow >= nrows) grow = nrows - 1;   // clamp; stores are guarded
    const float* xrow = X + (long)grow * K;

    for (int kc = 0; kc < K; kc += 64) {
        if (kc) __syncthreads();
        #pragma unroll
        for (int i = 0; i < 4; ++i) {
            const int o = tid * 4 + i * 1024;
            *(float4*)&sW[o] = *(const float4*)&W[(long)kc * 64 + o];
        }
        #pragma unroll
        for (int t = 0; t < 4; ++t) {
            const int k = lq * 16 + t * 4;
            const float4 v = *(const float4*)&xrow[kc + k];
            sX[(k + 0) * 64 + lr] = v.x;
            sX[(k + 1) * 64 + lr] = v.y;
            sX[(k + 2) * 64 + lr] = v.z;
            sX[(k + 3) * 64 + lr] = v.w;
        }
        __syncthreads();
        #pragma unroll 4
        for (int k = 0; k < 64; ++k) {
            const float4 xv = *(const float4*)&sX[k * 64 + ty * 4];
            const float4 wv = *(const float4*)&sW[k * 64 + tx * 4];
            acc[0]  = fmaf(xv.x, wv.x, acc[0]);
            acc[1]  = fmaf(xv.x, wv.y, acc[1]);
            acc[2]  = fmaf(xv.x, wv.z, acc[2]);
            acc[3]  = fmaf(xv.x, wv.w, acc[3]);
            acc[4]  = fmaf(xv.y, wv.x, acc[4]);
            acc[5]  = fmaf(xv.y, wv.y, acc[5]);
            acc[6]  = fmaf(xv.y, wv.z, acc[6]);
            acc[7]  = fmaf(xv.y, wv.w, acc[7]);
            acc[8]  = fmaf(xv.z, wv.x, acc[8]);
            acc[9]  = fmaf(xv.z, wv.y, acc[9]);
            acc[10] = fmaf(xv.z, wv.z, acc[10]);
            acc[11] = fmaf(xv.z, wv.w, acc[11]);
            acc[12] = fmaf(xv.w, wv.x, acc[12]);
            acc[13] = fmaf(xv.w, wv.y, acc[13]);
            acc[14] = fmaf(xv.w, wv.z, acc[14]);
            acc[15] = fmaf(xv.w, wv.w, acc[15]);
        }
    }

    #pragma unroll
    for (int i = 0; i < 4; ++i) {
        const int orow = rowbase + ty * 4 + i;
        if (orow < nrows) {
            const float d = rowscale[orow];
            ushort4 ov;
            ov.x = f2bf(d * acc[i * 4 + 0]);
            ov.y = f2bf(d * acc[i * 4 + 1]);
            ov.z = f2bf(d * acc[i * 4 + 2]);
            ov.w = f2bf(d * acc[i * 4 + 3]);
            *(ushort4*)&Y[(long)orow * 64 + tx * 4] = ov;
        }
    }
}

// Edge-parallel aggregation. Block k owns nodes [k*64, k*64+64) (quarter of
// sort-bucket k>>2). fp32 LDS accum[64][65] seeded with self-loop rows.
// 8 lanes per edge: 16B bf16 gather + 8 ds_add_f32 (predicated on the edge
// belonging to this slice). Node-parallel epilogue: dis/bias/relu/pack.
template <bool RELU, bool OUT_BF16>
__global__ __launch_bounds__(256) void agg_fused(const unsigned short* __restrict__ xs,
                                                 const int2* __restrict__ part,
                                                 const int* __restrict__ offsBM,
                                                 const float* __restrict__ dis,
                                                 const float* __restrict__ bias,
                                                 void* __restrict__ out, int N, int E) {
    __shared__ float accum[64 * 65];
    const int t = threadIdx.x;
    const int base = blockIdx.x << 6;
    const int bkt = blockIdx.x >> 2;
    const int bstart = offsBM[bkt * NC];
    const int bend = (bkt + 1 < NBPAD) ? offsBM[(bkt + 1) * NC] : E;

    {   // seed with self-loop row (xs already = dis*xw); OOB nodes: garbage, unused
        const int node = t >> 2, fq = t & 3;
        const unsigned short* p = &xs[(size_t)(base + node) * 64 + fq * 16];
        const uint4 q0 = *(const uint4*)p;
        const uint4 q1 = *(const uint4*)(p + 8);
        float* a = &accum[node * 65 + fq * 16];
        a[0] = bflo(q0.x); a[1] = bfhi(q0.x); a[2] = bflo(q0.y); a[3] = bfhi(q0.y);
        a[4] = bflo(q0.z); a[5] = bfhi(q0.z); a[6] = bflo(q0.w); a[7] = bfhi(q0.w);
        a[8] = bflo(q1.x); a[9] = bfhi(q1.x); a[10] = bflo(q1.y); a[11] = bfhi(q1.y);
        a[12] = bflo(q1.z); a[13] = bfhi(q1.z); a[14] = bflo(q1.w); a[15] = bfhi(q1.w);
    }
    __syncthreads();

    const int g = t >> 3;        // 32 edge groups per block
    const int fl = t & 7;        // 8 lanes x 16B per edge row
    for (int i = bstart + g; i < bend; i += 32) {
        const int2 ec = part[i];
        const unsigned d = (unsigned)(ec.y - base);
        if (d < 64u) {
            const uint4 q = *(const uint4*)&xs[(size_t)ec.x * 64 + fl * 8];
            float* a = &accum[d * 65 + fl * 8];
            atomicAdd(&a[0], bflo(q.x)); atomicAdd(&a[1], bfhi(q.x));
            atomicAdd(&a[2], bflo(q.y)); atomicAdd(&a[3], bfhi(q.y));
            atomicAdd(&a[4], bflo(q.z)); atomicAdd(&a[5], bfhi(q.z));
            atomicAdd(&a[6], bflo(q.w)); atomicAdd(&a[7], bfhi(q.w));
        }
    }
    __syncthreads();

    const int node = t >> 2, fq = t & 3;
    if (base + node < N) {
        const float di = dis[base + node];
        const float* a = &accum[node * 65 + fq * 16];
        float o[16];
        #pragma unroll
        for (int j = 0; j < 16; ++j) {
            o[j] = fmaf(a[j], di, bias[fq * 16 + j]);
            if (RELU) o[j] = fmaxf(o[j], 0.f);
        }
        if (OUT_BF16) {
            uint4 q0, q1;
            q0.x = (unsigned)f2bf(o[0]) | ((unsigned)f2bf(o[1]) << 16);
            q0.y = (unsigned)f2bf(o[2]) | ((unsigned)f2bf(o[3]) << 16);
            q0.z = (unsigned)f2bf(o[4]) | ((unsigned)f2bf(o[5]) << 16);
            q0.w = (unsigned)f2bf(o[6]) | ((unsigned)f2bf(o[7]) << 16);
            q1.x = (unsigned)f2bf(o[8]) | ((unsigned)f2bf(o[9]) << 16);
            q1.y = (unsigned)f2bf(o[10]) | ((unsigned)f2bf(o[11]) << 16);
            q1.z = (unsigned)f2bf(o[12]) | ((unsigned)f2bf(o[13]) << 16);
            q1.w = (unsigned)f2bf(o[14]) | ((unsigned)f2bf(o[15]) << 16);
            unsigned short* op = (unsigned short*)out + (size_t)(base + node) * 64 + fq * 16;
            *(uint4*)&op[0] = q0;
            *(uint4*)&op[8] = q1;
        } else {
            float* op = (float*)out + (size_t)(base + node) * 64 + fq * 16;
            *(float4*)&op[0] = make_float4(o[0], o[1], o[2], o[3]);
            *(float4*)&op[4] = make_float4(o[4], o[5], o[6], o[7]);
            *(float4*)&op[8] = make_float4(o[8], o[9], o[10], o[11]);
            *(float4*)&op[12] = make_float4(o[12], o[13], o[14], o[15]);
        }
    }
}

// 8 lanes per label edge (32 edges/wave): 16B bf16 gathers; 3-step xor reduce.
__global__ __launch_bounds__(256) void decode_kernel(const unsigned short* __restrict__ z,
                                                     const int* __restrict__ src,
                                                     const int* __restrict__ dst,
                                                     float* __restrict__ out, int L) {
    const int t = blockIdx.x * 256 + threadIdx.x;
    const int e = t >> 3;
    const int fl = t & 7;
    if (e >= L) return;
    const int s = src[e];
    const int d = dst[e];
    const uint4 qa = *(const uint4*)&z[(long)s * 64 + fl * 8];
    const uint4 qb = *(const uint4*)&z[(long)d * 64 + fl * 8];
    float p = bflo(qa.x) * bflo(qb.x) + bfhi(qa.x) * bfhi(qb.x)
            + bflo(qa.y) * bflo(qb.y) + bfhi(qa.y) * bfhi(qb.y)
            + bflo(qa.z) * bflo(qb.z) + bfhi(qa.z) * bfhi(qb.z)
            + bflo(qa.w) * bflo(qb.w) + bfhi(qa.w) * bfhi(qb.w);
    p += __shfl_xor(p, 4); p += __shfl_xor(p, 2); p += __shfl_xor(p, 1);
    if (fl == 0) out[e] = p;
}

extern "C" void kernel_launch(void* const* d_in, const int* in_sizes, int n_in,
                              void* d_out, int out_size, void* d_ws, size_t ws_size,
                              hipStream_t stream) {
    const float* x   = (const float*)d_in[0];
    const int*   ei  = (const int*)d_in[1];
    const int*   eli = (const int*)d_in[2];
    const float* W1  = (const float*)d_in[3];
    const float* b1  = (const float*)d_in[4];
    const float* W2  = (const float*)d_in[5];
    const float* b2  = (const float*)d_in[6];
    float* out = (float*)d_out;

    const int N = in_sizes[0] / 256;   // 50000 nodes (IN_CH = 256)
    const int E = in_sizes[1] / 2;     // 800000 edges
    const int L = in_sizes[2] / 2;     // 200000 label edges
    const int* row = ei;
    const int* col = ei + E;
    const int* src = eli;
    const int* dst = eli + L;

    char* w = (char*)d_ws;
    unsigned short* xs = (unsigned short*)w;  w += (size_t)N * 64 * 2;  // bf16 pre-agg feats
    float* h   = (float*)w;  w += (size_t)N * 64 * 4;                   // layer-1 output (fp32)
    unsigned short* z = (unsigned short*)w;  w += (size_t)N * 64 * 2;   // bf16 layer-2 output
    int2*  part = (int2*)w;  w += (size_t)E * 8;          // bucket-partitioned edges
    float* dis  = (float*)w; w += (size_t)((N + 63) & ~63) * 4;  // rsqrt(deg+1)
    int* histCM = (int*)w;   w += (size_t)NC * NBPAD * 4; // per-(chunk,bucket) counts
    int* offsBM = (int*)w;   w += (size_t)NBPAD * NC * 4; // per-(bucket,chunk) offsets
    int* bsums  = (int*)w;   w += NBPAD * 4;              // bucket totals

    const int CE = (E + NC - 1) / NC;
    const int nbk = (N + (1 << BSHIFT) - 1) >> BSHIFT;    // 196 buckets
    const int nslice = (N + 63) >> 6;                     // 782 agg slices

    hipMemsetAsync(bsums, 0, NBPAD * sizeof(int), stream);
    hist_kernel<<<NC, 256, 0, stream>>>(col, histCM, bsums, E, CE);
    rowscan_kernel<<<NBPAD, 256, 0, stream>>>(histCM, bsums, offsBM);
    reorder_kernel<<<NC, 256, 0, stream>>>(row, col, offsBM, part, E, CE);
    bucket_deg_kernel<<<nbk, 256, 0, stream>>>(part, offsBM, dis, N, E);

    gemm_tile<256><<<(N + 63) / 64, 256, 0, stream>>>(x, W1, dis, xs, N);
    agg_fused<true, false><<<nslice, 256, 0, stream>>>(xs, part, offsBM, dis, b1, h, N, E);
    gemm_tile<64><<<(N + 63) / 64, 256, 0, stream>>>(h, W2, dis, xs, N);
    agg_fused<false, true><<<nslice, 256, 0, stream>>>(xs, part, offsBM, dis, b2, z, N, E);
    decode_kernel<<<(L * 8 + 255) / 256, 256, 0, stream>>>(z, src, dst, out, L);
}

// Round 10
// 235.131 us; speedup vs baseline: 3.6803x; 3.6803x over previous
//
#include <hip/hip_runtime.h>
#include <hip/hip_bf16.h>

// ---------------------------------------------------------------------------
// GCN: h = relu(gcnconv(x,W1,b1)); z = gcnconv(h,W2,b2); out[e]=dot(z[s],z[d])
// CSR build = bucketed counting sort, 4 kernels: hist(+bucket sums via
// atomics) -> rowscan(bucket-base reduce folded in) -> reorder -> bucket_csr.
// All random writes land in block-owned windows (full-line writebacks).
// GEMM epilogue pre-scales rows by dis and packs to BF16 (gathered tables
// are 128B/row). Aggregation: one wave per node, 4 groups x 16 lanes x
// float4, 2-deep unrolled (R7 structure - best measured: 223us).
// R9's edge-parallel LDS-atomic agg was 7x WORSE (353us/dispatch): dependent
// part->gather->ds_add chains don't pipeline; slice predication wastes 75%.
// Agg batches 64 edge indices per wave via LDS (ds_read broadcast is
// exec-mask safe; __shfl from tail-inactive lanes is NOT - R5 failure).
// ---------------------------------------------------------------------------

constexpr int NC = 512;      // edge chunks (= hist/reorder grid)
constexpr int NBPAD = 256;   // padded bucket count (>= 196 actual)
constexpr int BSHIFT = 8;    // 256 nodes per bucket (64B reorder runs)

__device__ __forceinline__ unsigned short f2bf(float f) {   // RNE
    unsigned u = __float_as_uint(f);
    return (unsigned short)((u + 0x7FFF + ((u >> 16) & 1)) >> 16);
}
__device__ __forceinline__ float bf2f(unsigned short h) {
    return __uint_as_float(((unsigned)h) << 16);
}
__device__ __forceinline__ float4 bf4_to_f4(ushort4 u) {
    return make_float4(bf2f(u.x), bf2f(u.y), bf2f(u.z), bf2f(u.w));
}

// histCM[c*NBPAD+b] = bucket-b count in chunk c; bsums[b] = bucket totals.
__global__ __launch_bounds__(256) void hist_kernel(const int* __restrict__ col,
                                                   int* __restrict__ histCM,
                                                   int* __restrict__ bsums, int E, int CE) {
    __shared__ int hl[NBPAD];
    const int t = threadIdx.x, c = blockIdx.x;
    hl[t] = 0;
    __syncthreads();
    const int s = c * CE, e = min(E, s + CE);
    for (int i = s + t; i < e; i += 256) atomicAdd(&hl[col[i] >> BSHIFT], 1);
    __syncthreads();
    const int v = hl[t];
    histCM[c * NBPAD + t] = v;
    if (v) atomicAdd(&bsums[t], v);
}

// Block b: bucket base = sum(bsums[k<b]) (masked reduce), then exclusive scan
// of the bucket's NC chunk counts (2/thread) -> offsBM[b*NC+c].
__global__ __launch_bounds__(256) void rowscan_kernel(const int* __restrict__ histCM,
                                                      const int* __restrict__ bsums,
                                                      int* __restrict__ offsBM) {
    __shared__ int red[256];
    __shared__ int sc[256];
    const int t = threadIdx.x, b = blockIdx.x;
    red[t] = (t < b) ? bsums[t] : 0;
    __syncthreads();
    for (int off = 128; off > 0; off >>= 1) {
        if (t < off) red[t] += red[t + off];
        __syncthreads();
    }
    const int base = red[0];
    const int a0 = histCM[(2 * t) * NBPAD + b];
    const int a1 = histCM[(2 * t + 1) * NBPAD + b];
    const int ps = a0 + a1;
    sc[t] = ps;
    __syncthreads();
    for (int off = 1; off < 256; off <<= 1) {
        int u = (t >= off) ? sc[t - off] : 0;
        __syncthreads();
        sc[t] += u;
        __syncthreads();
    }
    const int excl = sc[t] - ps;
    offsBM[b * NC + 2 * t] = base + excl;
    offsBM[b * NC + 2 * t + 1] = base + excl + a0;
}

// Scatter (row,col) pairs into per-(bucket,chunk) contiguous runs of part[].
__global__ __launch_bounds__(256) void reorder_kernel(const int* __restrict__ row,
                                                      const int* __restrict__ col,
                                                      const int* __restrict__ offsBM,
                                                      int2* __restrict__ part, int E, int CE) {
    __shared__ int cur[NBPAD];
    const int t = threadIdx.x, c = blockIdx.x;
    cur[t] = offsBM[t * NC + c];
    __syncthreads();
    const int s = c * CE, e = min(E, s + CE);
    for (int i = s + t; i < e; i += 256) {
        const int r = row[i], cl = col[i];
        const int p = atomicAdd(&cur[cl >> BSHIFT], 1);
        part[p] = make_int2(r, cl);
    }
}

// One block per bucket: LDS degree count -> LDS scan -> offs/dis -> scatter
// rows into the bucket's private csr window.
__global__ __launch_bounds__(256) void bucket_csr_kernel(const int2* __restrict__ part,
                                                         const int* __restrict__ offsBM,
                                                         int* __restrict__ csr,
                                                         int* __restrict__ offs,
                                                         float* __restrict__ dis,
                                                         int N, int E, int nbk) {
    __shared__ int cnt[256];
    __shared__ int sc[256];
    const int t = threadIdx.x, b = blockIdx.x;
    const int base = b << BSHIFT;
    const int bstart = offsBM[b * NC];
    const int bend = (b + 1 < NBPAD) ? offsBM[(b + 1) * NC] : E;
    const int m = bend - bstart;
    cnt[t] = 0;
    __syncthreads();
    for (int i = t; i < m; i += 256) atomicAdd(&cnt[part[bstart + i].y - base], 1);
    __syncthreads();
    const int v = cnt[t];
    sc[t] = v;
    __syncthreads();
    for (int off = 1; off < 256; off <<= 1) {
        int u = (t >= off) ? sc[t - off] : 0;
        __syncthreads();
        sc[t] += u;
        __syncthreads();
    }
    const int excl = sc[t] - v;
    const int node = base + t;
    if (node < N) {
        offs[node] = bstart + excl;
        dis[node] = rsqrtf((float)(v + 1));   // +1 = self loop
    }
    sc[t] = excl;          // repurpose as scatter cursor
    __syncthreads();
    for (int i = t; i < m; i += 256) {
        const int2 ec = part[bstart + i];
        const int p = atomicAdd(&sc[ec.y - base], 1);
        csr[bstart + p] = ec.x;
    }
    if (b == nbk - 1 && t == 0) offs[N] = E;
}

// Y[N,64] (bf16) = rowscale[r] * (X[N,K] @ W[K,64]).
// Block = 256 thr = 16x16 grid; 4x4 register micro-tile; both operands in
// LDS (k-major); per k: 2 ds_read_b128 + 16 FMAs, no global loads in k-loop.
template <int K>
__global__ __launch_bounds__(256) void gemm_tile(const float* __restrict__ X,
                                                 const float* __restrict__ W,
                                                 const float* __restrict__ rowscale,
                                                 unsigned short* __restrict__ Y, int nrows) {
    __shared__ float sX[64 * 64];
    __shared__ float sW[64 * 64];
    const int tid = threadIdx.x;
    const int tx = tid & 15;         // col group
    const int ty = tid >> 4;         // row group
    const int rowbase = blockIdx.x * 64;

    float acc[16];
    #pragma unroll
    for (int i = 0; i < 16; ++i) acc[i] = 0.f;

    const int lr = tid & 63;         // loader row (0..63)
    const int lq = tid >> 6;         // loader k-quarter (16 k's each)
    int grow = rowbase + lr;
    if (grow >= nrows) grow = nrows - 1;   // clamp; stores are guarded
    const float* xrow = X + (long)grow * K;

    for (int kc = 0; kc < K; kc += 64) {
        if (kc) __syncthreads();
        #pragma unroll
        for (int i = 0; i < 4; ++i) {
            const int o = tid * 4 + i * 1024;
            *(float4*)&sW[o] = *(const float4*)&W[(long)kc * 64 + o];
        }
        #pragma unroll
        for (int t = 0; t < 4; ++t) {
            const int k = lq * 16 + t * 4;
            const float4 v = *(const float4*)&xrow[kc + k];
            sX[(k + 0) * 64 + lr] = v.x;
            sX[(k + 1) * 64 + lr] = v.y;
            sX[(k + 2) * 64 + lr] = v.z;
            sX[(k + 3) * 64 + lr] = v.w;
        }
        __syncthreads();
        #pragma unroll 4
        for (int k = 0; k < 64; ++k) {
            const float4 xv = *(const float4*)&sX[k * 64 + ty * 4];
            const float4 wv = *(const float4*)&sW[k * 64 + tx * 4];
            acc[0]  = fmaf(xv.x, wv.x, acc[0]);
            acc[1]  = fmaf(xv.x, wv.y, acc[1]);
            acc[2]  = fmaf(xv.x, wv.z, acc[2]);
            acc[3]  = fmaf(xv.x, wv.w, acc[3]);
            acc[4]  = fmaf(xv.y, wv.x, acc[4]);
            acc[5]  = fmaf(xv.y, wv.y, acc[5]);
            acc[6]  = fmaf(xv.y, wv.z, acc[6]);
            acc[7]  = fmaf(xv.y, wv.w, acc[7]);
            acc[8]  = fmaf(xv.z, wv.x, acc[8]);
            acc[9]  = fmaf(xv.z, wv.y, acc[9]);
            acc[10] = fmaf(xv.z, wv.z, acc[10]);
            acc[11] = fmaf(xv.z, wv.w, acc[11]);
            acc[12] = fmaf(xv.w, wv.x, acc[12]);
            acc[13] = fmaf(xv.w, wv.y, acc[13]);
            acc[14] = fmaf(xv.w, wv.z, acc[14]);
            acc[15] = fmaf(xv.w, wv.w, acc[15]);
        }
    }

    #pragma unroll
    for (int i = 0; i < 4; ++i) {
        const int orow = rowbase + ty * 4 + i;
        if (orow < nrows) {
            const float d = rowscale[orow];
            ushort4 ov;
            ov.x = f2bf(d * acc[i * 4 + 0]);
            ov.y = f2bf(d * acc[i * 4 + 1]);
            ov.z = f2bf(d * acc[i * 4 + 2]);
            ov.w = f2bf(d * acc[i * 4 + 3]);
            *(ushort4*)&Y[(long)orow * 64 + tx * 4] = ov;
        }
    }
}

// One wave per node, 4 groups of 16 lanes (lane fl owns feats fl*4..+3).
// xs is bf16 (128B/row). Batch: 64 edge indices loaded coalesced into LDS;
// inner loop has ONLY the 128B row gather (2 in flight per group).
// OUT_BF16: agg1 -> fp32 h (dense, feeds gemm2); agg2 -> bf16 z (gathered).
template <bool RELU, bool OUT_BF16>
__global__ __launch_bounds__(256) void agg_kernel(const unsigned short* __restrict__ xs,
                                                  const int* __restrict__ csr,
                                                  const int* __restrict__ offs,
                                                  const float* __restrict__ dis,
                                                  const float* __restrict__ bias,
                                                  void* __restrict__ out, int n) {
    __shared__ int sidx[4][64];
    const int wv = threadIdx.x >> 6;
    const int lane = threadIdx.x & 63;
    const int grp = lane >> 4;
    const int fl = lane & 15;
    const int i = blockIdx.x * 4 + wv;
    if (i >= n) return;
    float4 acc = make_float4(0.f, 0.f, 0.f, 0.f);
    if (grp == 0)    // self loop counted once (xs already = dis*xw)
        acc = bf4_to_f4(*(const ushort4*)&xs[(long)i * 64 + fl * 4]);
    const int s = offs[i];
    const int e = offs[i + 1];
    for (int jb = s; jb < e; jb += 64) {
        const int nb = min(64, e - jb);
        if (lane < nb) sidx[wv][lane] = csr[jb + lane];
        // same-wave DS ops are processed in order: reads below see the writes
        int u = grp;
        for (; u + 4 < nb; u += 8) {
            const int r0 = sidx[wv][u];
            const int r1 = sidx[wv][u + 4];
            const float4 v0 = bf4_to_f4(*(const ushort4*)&xs[(long)r0 * 64 + fl * 4]);
            const float4 v1 = bf4_to_f4(*(const ushort4*)&xs[(long)r1 * 64 + fl * 4]);
            acc.x += v0.x + v1.x; acc.y += v0.y + v1.y;
            acc.z += v0.z + v1.z; acc.w += v0.w + v1.w;
        }
        for (; u < nb; u += 4) {
            const int r0 = sidx[wv][u];
            const float4 v0 = bf4_to_f4(*(const ushort4*)&xs[(long)r0 * 64 + fl * 4]);
            acc.x += v0.x; acc.y += v0.y; acc.z += v0.z; acc.w += v0.w;
        }
    }
    acc.x += __shfl_xor(acc.x, 16); acc.y += __shfl_xor(acc.y, 16);
    acc.z += __shfl_xor(acc.z, 16); acc.w += __shfl_xor(acc.w, 16);
    acc.x += __shfl_xor(acc.x, 32); acc.y += __shfl_xor(acc.y, 32);
    acc.z += __shfl_xor(acc.z, 32); acc.w += __shfl_xor(acc.w, 32);
    if (grp == 0) {
        const float di = dis[i];
        const float4 b = *(const float4*)&bias[fl * 4];
        float4 o;
        o.x = fmaf(acc.x, di, b.x); o.y = fmaf(acc.y, di, b.y);
        o.z = fmaf(acc.z, di, b.z); o.w = fmaf(acc.w, di, b.w);
        if (RELU) {
            o.x = fmaxf(o.x, 0.f); o.y = fmaxf(o.y, 0.f);
            o.z = fmaxf(o.z, 0.f); o.w = fmaxf(o.w, 0.f);
        }
        if (OUT_BF16) {
            ushort4 ov;
            ov.x = f2bf(o.x); ov.y = f2bf(o.y); ov.z = f2bf(o.z); ov.w = f2bf(o.w);
            *(ushort4*)&((unsigned short*)out)[(long)i * 64 + fl * 4] = ov;
        } else {
            *(float4*)&((float*)out)[(long)i * 64 + fl * 4] = o;
        }
    }
}

// 16 lanes per label edge: bf16 gathers of z[src], z[dst]; 4-step xor reduce.
__global__ __launch_bounds__(256) void decode_kernel(const unsigned short* __restrict__ z,
                                                     const int* __restrict__ src,
                                                     const int* __restrict__ dst,
                                                     float* __restrict__ out, int L) {
    const int t = blockIdx.x * 256 + threadIdx.x;
    const int e = t >> 4;
    const int fl = t & 15;
    if (e >= L) return;
    const int s = src[e];
    const int d = dst[e];
    const float4 a = bf4_to_f4(*(const ushort4*)&z[(long)s * 64 + fl * 4]);
    const float4 b = bf4_to_f4(*(const ushort4*)&z[(long)d * 64 + fl * 4]);
    float p = a.x * b.x + a.y * b.y + a.z * b.z + a.w * b.w;
    p += __shfl_xor(p, 8); p += __shfl_xor(p, 4);
    p += __shfl_xor(p, 2); p += __shfl_xor(p, 1);
    if (fl == 0) out[e] = p;
}

extern "C" void kernel_launch(void* const* d_in, const int* in_sizes, int n_in,
                              void* d_out, int out_size, void* d_ws, size_t ws_size,
                              hipStream_t stream) {
    const float* x   = (const float*)d_in[0];
    const int*   ei  = (const int*)d_in[1];
    const int*   eli = (const int*)d_in[2];
    const float* W1  = (const float*)d_in[3];
    const float* b1  = (const float*)d_in[4];
    const float* W2  = (const float*)d_in[5];
    const float* b2  = (const float*)d_in[6];
    float* out = (float*)d_out;

    const int N = in_sizes[0] / 256;   // 50000 nodes (IN_CH = 256)
    const int E = in_sizes[1] / 2;     // 800000 edges
    const int L = in_sizes[2] / 2;     // 200000 label edges
    const int* row = ei;
    const int* col = ei + E;
    const int* src = eli;
    const int* dst = eli + L;

    char* w = (char*)d_ws;
    unsigned short* xs = (unsigned short*)w;  w += (size_t)N * 64 * 2;  // bf16 pre-agg feats
    float* h   = (float*)w;  w += (size_t)N * 64 * 4;                   // layer-1 output (fp32)
    unsigned short* z = (unsigned short*)w;  w += (size_t)N * 64 * 2;   // bf16 layer-2 output
    int*   csr = (int*)w;    w += (size_t)E * 4;          // sources sorted by target
    int*   offs = (int*)w;   w += (size_t)(N + 1) * 4;    // CSR offsets (N+1)
    float* dis = (float*)w;  w += (size_t)N * 4;          // rsqrt(deg+1)
    int2*  part = (int2*)w;  w += (size_t)E * 8;          // reorder staging
    int* histCM = (int*)w;   w += (size_t)NC * NBPAD * 4; // per-(chunk,bucket) counts
    int* offsBM = (int*)w;   w += (size_t)NBPAD * NC * 4; // per-(bucket,chunk) offsets
    int* bsums  = (int*)w;   w += NBPAD * 4;              // bucket totals

    const int CE = (E + NC - 1) / NC;
    const int nbk = (N + (1 << BSHIFT) - 1) >> BSHIFT;    // 196 buckets

    hipMemsetAsync(bsums, 0, NBPAD * sizeof(int), stream);
    hist_kernel<<<NC, 256, 0, stream>>>(col, histCM, bsums, E, CE);
    rowscan_kernel<<<NBPAD, 256, 0, stream>>>(histCM, bsums, offsBM);
    reorder_kernel<<<NC, 256, 0, stream>>>(row, col, offsBM, part, E, CE);
    bucket_csr_kernel<<<nbk, 256, 0, stream>>>(part, offsBM, csr, offs, dis, N, E, nbk);

    gemm_tile<256><<<(N + 63) / 64, 256, 0, stream>>>(x, W1, dis, xs, N);
    agg_kernel<true, false><<<(N + 3) / 4, 256, 0, stream>>>(xs, csr, offs, dis, b1, h, N);
    gemm_tile<64><<<(N + 63) / 64, 256, 0, stream>>>(h, W2, dis, xs, N);
    agg_kernel<false, true><<<(N + 3) / 4, 256, 0, stream>>>(xs, csr, offs, dis, b2, z, N);
    decode_kernel<<<(L + 15) / 16, 256, 0, stream>>>(z, src, dst, out, L);
}

// Round 11
// 224.908 us; speedup vs baseline: 3.8476x; 1.0455x over previous
//
#include <hip/hip_runtime.h>
#include <hip/hip_bf16.h>

// ---------------------------------------------------------------------------
// GCN: h = relu(gcnconv(x,W1,b1)); z = gcnconv(h,W2,b2); out[e]=dot(z[s],z[d])
// CSR build = bucketed counting sort, 4 kernels: hist(+bucket sums) ->
// rowscan -> reorder -> bucket_csr. part entries packed (row<<8 | col&255).
// GEMM epilogue pre-scales rows by dis and packs to BF16 (128B/row tables).
// Aggregation: one 16-LANE GROUP per node (features lane-parallel, 8B/lane)
// -> NO reduction, NO LDS, 4 independent node-chains per wave, 4-deep
// unrolled gathers (up to 16 loads in flight/wave). Latency-bound at the
// 8-wave/SIMD occupancy cap, so per-wave MLP is the lever (R7-R10 evidence).
// R9 lesson: edge-parallel LDS-atomic agg is 7x worse (dependent ds_add
// chains). R5 lesson: no __shfl across group-divergent tails.
// ---------------------------------------------------------------------------

constexpr int NC = 512;      // edge chunks (= hist/reorder grid)
constexpr int NBPAD = 256;   // padded bucket count (>= 196 actual)
constexpr int BSHIFT = 8;    // 256 nodes per bucket

__device__ __forceinline__ unsigned short f2bf(float f) {   // RNE
    unsigned u = __float_as_uint(f);
    return (unsigned short)((u + 0x7FFF + ((u >> 16) & 1)) >> 16);
}
__device__ __forceinline__ float bf2f(unsigned short h) {
    return __uint_as_float(((unsigned)h) << 16);
}
__device__ __forceinline__ float4 bf4_to_f4(ushort4 u) {
    return make_float4(bf2f(u.x), bf2f(u.y), bf2f(u.z), bf2f(u.w));
}

// histCM[c*NBPAD+b] = bucket-b count in chunk c; bsums[b] = bucket totals.
__global__ __launch_bounds__(256) void hist_kernel(const int* __restrict__ col,
                                                   int* __restrict__ histCM,
                                                   int* __restrict__ bsums, int E, int CE) {
    __shared__ int hl[NBPAD];
    const int t = threadIdx.x, c = blockIdx.x;
    hl[t] = 0;
    __syncthreads();
    const int s = c * CE, e = min(E, s + CE);
    for (int i = s + t; i < e; i += 256) atomicAdd(&hl[col[i] >> BSHIFT], 1);
    __syncthreads();
    const int v = hl[t];
    histCM[c * NBPAD + t] = v;
    if (v) atomicAdd(&bsums[t], v);
}

// Block b: bucket base = sum(bsums[k<b]) (masked reduce), then exclusive scan
// of the bucket's NC chunk counts (2/thread) -> offsBM[b*NC+c].
__global__ __launch_bounds__(256) void rowscan_kernel(const int* __restrict__ histCM,
                                                      const int* __restrict__ bsums,
                                                      int* __restrict__ offsBM) {
    __shared__ int red[256];
    __shared__ int sc[256];
    const int t = threadIdx.x, b = blockIdx.x;
    red[t] = (t < b) ? bsums[t] : 0;
    __syncthreads();
    for (int off = 128; off > 0; off >>= 1) {
        if (t < off) red[t] += red[t + off];
        __syncthreads();
    }
    const int base = red[0];
    const int a0 = histCM[(2 * t) * NBPAD + b];
    const int a1 = histCM[(2 * t + 1) * NBPAD + b];
    const int ps = a0 + a1;
    sc[t] = ps;
    __syncthreads();
    for (int off = 1; off < 256; off <<= 1) {
        int u = (t >= off) ? sc[t - off] : 0;
        __syncthreads();
        sc[t] += u;
        __syncthreads();
    }
    const int excl = sc[t] - ps;
    offsBM[b * NC + 2 * t] = base + excl;
    offsBM[b * NC + 2 * t + 1] = base + excl + a0;
}

// Scatter packed (row<<8 | col&255) into per-(bucket,chunk) runs of part[].
__global__ __launch_bounds__(256) void reorder_kernel(const int* __restrict__ row,
                                                      const int* __restrict__ col,
                                                      const int* __restrict__ offsBM,
                                                      int* __restrict__ part, int E, int CE) {
    __shared__ int cur[NBPAD];
    const int t = threadIdx.x, c = blockIdx.x;
    cur[t] = offsBM[t * NC + c];
    __syncthreads();
    const int s = c * CE, e = min(E, s + CE);
    for (int i = s + t; i < e; i += 256) {
        const int r = row[i], cl = col[i];
        const int p = atomicAdd(&cur[cl >> BSHIFT], 1);
        part[p] = (r << 8) | (cl & 255);   // row < 65536 fits 16 bits
    }
}

// One block per bucket: LDS degree count -> LDS scan -> offs/dis -> scatter
// rows into the bucket's private csr window.
__global__ __launch_bounds__(256) void bucket_csr_kernel(const int* __restrict__ part,
                                                         const int* __restrict__ offsBM,
                                                         int* __restrict__ csr,
                                                         int* __restrict__ offs,
                                                         float* __restrict__ dis,
                                                         int N, int E, int nbk) {
    __shared__ int cnt[256];
    __shared__ int sc[256];
    const int t = threadIdx.x, b = blockIdx.x;
    const int base = b << BSHIFT;
    const int bstart = offsBM[b * NC];
    const int bend = (b + 1 < NBPAD) ? offsBM[(b + 1) * NC] : E;
    const int m = bend - bstart;
    cnt[t] = 0;
    __syncthreads();
    for (int i = t; i < m; i += 256) atomicAdd(&cnt[part[bstart + i] & 255], 1);
    __syncthreads();
    const int v = cnt[t];
    sc[t] = v;
    __syncthreads();
    for (int off = 1; off < 256; off <<= 1) {
        int u = (t >= off) ? sc[t - off] : 0;
        __syncthreads();
        sc[t] += u;
        __syncthreads();
    }
    const int excl = sc[t] - v;
    const int node = base + t;
    if (node < N) {
        offs[node] = bstart + excl;
        dis[node] = rsqrtf((float)(v + 1));   // +1 = self loop
    }
    sc[t] = excl;          // repurpose as scatter cursor
    __syncthreads();
    for (int i = t; i < m; i += 256) {
        const int pc = part[bstart + i];
        const int p = atomicAdd(&sc[pc & 255], 1);
        csr[bstart + p] = pc >> 8;
    }
    if (b == nbk - 1 && t == 0) offs[N] = E;
}

// Y[N,64] (bf16) = rowscale[r] * (X[N,K] @ W[K,64]).
// Block = 256 thr = 16x16 grid; 4x4 register micro-tile; both operands in
// LDS (k-major); per k: 2 ds_read_b128 + 16 FMAs, no global loads in k-loop.
template <int K>
__global__ __launch_bounds__(256) void gemm_tile(const float* __restrict__ X,
                                                 const float* __restrict__ W,
                                                 const float* __restrict__ rowscale,
                                                 unsigned short* __restrict__ Y, int nrows) {
    __shared__ float sX[64 * 64];
    __shared__ float sW[64 * 64];
    const int tid = threadIdx.x;
    const int tx = tid & 15;         // col group
    const int ty = tid >> 4;         // row group
    const int rowbase = blockIdx.x * 64;

    float acc[16];
    #pragma unroll
    for (int i = 0; i < 16; ++i) acc[i] = 0.f;

    const int lr = tid & 63;         // loader row (0..63)
    const int lq = tid >> 6;         // loader k-quarter (16 k's each)
    int grow = rowbase + lr;
    if (grow >= nrows) grow = nrows - 1;   // clamp; stores are guarded
    const float* xrow = X + (long)grow * K;

    for (int kc = 0; kc < K; kc += 64) {
        if (kc) __syncthreads();
        #pragma unroll
        for (int i = 0; i < 4; ++i) {
            const int o = tid * 4 + i * 1024;
            *(float4*)&sW[o] = *(const float4*)&W[(long)kc * 64 + o];
        }
        #pragma unroll
        for (int t = 0; t < 4; ++t) {
            const int k = lq * 16 + t * 4;
            const float4 v = *(const float4*)&xrow[kc + k];
            sX[(k + 0) * 64 + lr] = v.x;
            sX[(k + 1) * 64 + lr] = v.y;
            sX[(k + 2) * 64 + lr] = v.z;
            sX[(k + 3) * 64 + lr] = v.w;
        }
        __syncthreads();
        #pragma unroll 4
        for (int k = 0; k < 64; ++k) {
            const float4 xv = *(const float4*)&sX[k * 64 + ty * 4];
            const float4 wv = *(const float4*)&sW[k * 64 + tx * 4];
            acc[0]  = fmaf(xv.x, wv.x, acc[0]);
            acc[1]  = fmaf(xv.x, wv.y, acc[1]);
            acc[2]  = fmaf(xv.x, wv.z, acc[2]);
            acc[3]  = fmaf(xv.x, wv.w, acc[3]);
            acc[4]  = fmaf(xv.y, wv.x, acc[4]);
            acc[5]  = fmaf(xv.y, wv.y, acc[5]);
            acc[6]  = fmaf(xv.y, wv.z, acc[6]);
            acc[7]  = fmaf(xv.y, wv.w, acc[7]);
            acc[8]  = fmaf(xv.z, wv.x, acc[8]);
            acc[9]  = fmaf(xv.z, wv.y, acc[9]);
            acc[10] = fmaf(xv.z, wv.z, acc[10]);
            acc[11] = fmaf(xv.z, wv.w, acc[11]);
            acc[12] = fmaf(xv.w, wv.x, acc[12]);
            acc[13] = fmaf(xv.w, wv.y, acc[13]);
            acc[14] = fmaf(xv.w, wv.z, acc[14]);
            acc[15] = fmaf(xv.w, wv.w, acc[15]);
        }
    }

    #pragma unroll
    for (int i = 0; i < 4; ++i) {
        const int orow = rowbase + ty * 4 + i;
        if (orow < nrows) {
            const float d = rowscale[orow];
            ushort4 ov;
            ov.x = f2bf(d * acc[i * 4 + 0]);
            ov.y = f2bf(d * acc[i * 4 + 1]);
            ov.z = f2bf(d * acc[i * 4 + 2]);
            ov.w = f2bf(d * acc[i * 4 + 3]);
            *(ushort4*)&Y[(long)orow * 64 + tx * 4] = ov;
        }
    }
}

// One 16-lane group per node; lane fl owns feats fl*4..+3 (8B bf16).
// Features are lane-parallel -> no reduction, no LDS. 4 independent node
// chains per wave; 4-deep unrolled gathers (16 loads in flight per wave).
// Consecutive groups = consecutive nodes -> csr reads share lines, stores
// coalesce. csr[j] read by all 16 lanes of a group = broadcast (1 request).
// OUT_BF16: agg1 -> fp32 h (dense, feeds gemm2); agg2 -> bf16 z (gathered).
template <bool RELU, bool OUT_BF16>
__global__ __launch_bounds__(256) void agg_kernel(const unsigned short* __restrict__ xs,
                                                  const int* __restrict__ csr,
                                                  const int* __restrict__ offs,
                                                  const float* __restrict__ dis,
                                                  const float* __restrict__ bias,
                                                  void* __restrict__ out, int n) {
    const int t = threadIdx.x;
    const int fl = t & 15;
    const int i = blockIdx.x * 16 + (t >> 4);   // node per 16-lane group
    if (i >= n) return;                          // no barriers below: safe
    float4 acc = bf4_to_f4(*(const ushort4*)&xs[(long)i * 64 + fl * 4]);  // self loop
    const int s = offs[i];
    const int e = offs[i + 1];
    int j = s;
    for (; j + 3 < e; j += 4) {
        const int r0 = csr[j],     r1 = csr[j + 1];
        const int r2 = csr[j + 2], r3 = csr[j + 3];
        const float4 v0 = bf4_to_f4(*(const ushort4*)&xs[(long)r0 * 64 + fl * 4]);
        const float4 v1 = bf4_to_f4(*(const ushort4*)&xs[(long)r1 * 64 + fl * 4]);
        const float4 v2 = bf4_to_f4(*(const ushort4*)&xs[(long)r2 * 64 + fl * 4]);
        const float4 v3 = bf4_to_f4(*(const ushort4*)&xs[(long)r3 * 64 + fl * 4]);
        acc.x += (v0.x + v1.x) + (v2.x + v3.x);
        acc.y += (v0.y + v1.y) + (v2.y + v3.y);
        acc.z += (v0.z + v1.z) + (v2.z + v3.z);
        acc.w += (v0.w + v1.w) + (v2.w + v3.w);
    }
    for (; j < e; ++j) {
        const int r0 = csr[j];
        const float4 v0 = bf4_to_f4(*(const ushort4*)&xs[(long)r0 * 64 + fl * 4]);
        acc.x += v0.x; acc.y += v0.y; acc.z += v0.z; acc.w += v0.w;
    }
    const float di = dis[i];
    const float4 b = *(const float4*)&bias[fl * 4];
    float4 o;
    o.x = fmaf(acc.x, di, b.x); o.y = fmaf(acc.y, di, b.y);
    o.z = fmaf(acc.z, di, b.z); o.w = fmaf(acc.w, di, b.w);
    if (RELU) {
        o.x = fmaxf(o.x, 0.f); o.y = fmaxf(o.y, 0.f);
        o.z = fmaxf(o.z, 0.f); o.w = fmaxf(o.w, 0.f);
    }
    if (OUT_BF16) {
        ushort4 ov;
        ov.x = f2bf(o.x); ov.y = f2bf(o.y); ov.z = f2bf(o.z); ov.w = f2bf(o.w);
        *(ushort4*)&((unsigned short*)out)[(long)i * 64 + fl * 4] = ov;
    } else {
        *(float4*)&((float*)out)[(long)i * 64 + fl * 4] = o;
    }
}

// 16 lanes per label edge: bf16 gathers of z[src], z[dst]; 4-step xor reduce
// (within-group shfl: all 16 source lanes share the group's control flow).
__global__ __launch_bounds__(256) void decode_kernel(const unsigned short* __restrict__ z,
                                                     const int* __restrict__ src,
                                                     const int* __restrict__ dst,
                                                     float* __restrict__ out, int L) {
    const int t = blockIdx.x * 256 + threadIdx.x;
    const int e = t >> 4;
    const int fl = t & 15;
    if (e >= L) return;
    const int s = src[e];
    const int d = dst[e];
    const float4 a = bf4_to_f4(*(const ushort4*)&z[(long)s * 64 + fl * 4]);
    const float4 b = bf4_to_f4(*(const ushort4*)&z[(long)d * 64 + fl * 4]);
    float p = a.x * b.x + a.y * b.y + a.z * b.z + a.w * b.w;
    p += __shfl_xor(p, 8); p += __shfl_xor(p, 4);
    p += __shfl_xor(p, 2); p += __shfl_xor(p, 1);
    if (fl == 0) out[e] = p;
}

extern "C" void kernel_launch(void* const* d_in, const int* in_sizes, int n_in,
                              void* d_out, int out_size, void* d_ws, size_t ws_size,
                              hipStream_t stream) {
    const float* x   = (const float*)d_in[0];
    const int*   ei  = (const int*)d_in[1];
    const int*   eli = (const int*)d_in[2];
    const float* W1  = (const float*)d_in[3];
    const float* b1  = (const float*)d_in[4];
    const float* W2  = (const float*)d_in[5];
    const float* b2  = (const float*)d_in[6];
    float* out = (float*)d_out;

    const int N = in_sizes[0] / 256;   // 50000 nodes (IN_CH = 256)
    const int E = in_sizes[1] / 2;     // 800000 edges
    const int L = in_sizes[2] / 2;     // 200000 label edges
    const int* row = ei;
    const int* col = ei + E;
    const int* src = eli;
    const int* dst = eli + L;

    char* w = (char*)d_ws;
    unsigned short* xs = (unsigned short*)w;  w += (size_t)N * 64 * 2;  // bf16 pre-agg feats
    float* h   = (float*)w;  w += (size_t)N * 64 * 4;                   // layer-1 output (fp32)
    unsigned short* z = (unsigned short*)w;  w += (size_t)N * 64 * 2;   // bf16 layer-2 output
    int*   csr = (int*)w;    w += (size_t)E * 4;          // sources sorted by target
    int*   offs = (int*)w;   w += (size_t)(N + 1) * 4;    // CSR offsets (N+1)
    float* dis = (float*)w;  w += (size_t)N * 4;          // rsqrt(deg+1)
    int*   part = (int*)w;   w += (size_t)E * 4;          // packed (row<<8|col&255)
    int* histCM = (int*)w;   w += (size_t)NC * NBPAD * 4; // per-(chunk,bucket) counts
    int* offsBM = (int*)w;   w += (size_t)NBPAD * NC * 4; // per-(bucket,chunk) offsets
    int* bsums  = (int*)w;   w += NBPAD * 4;              // bucket totals

    const int CE = (E + NC - 1) / NC;
    const int nbk = (N + (1 << BSHIFT) - 1) >> BSHIFT;    // 196 buckets

    hipMemsetAsync(bsums, 0, NBPAD * sizeof(int), stream);
    hist_kernel<<<NC, 256, 0, stream>>>(col, histCM, bsums, E, CE);
    rowscan_kernel<<<NBPAD, 256, 0, stream>>>(histCM, bsums, offsBM);
    reorder_kernel<<<NC, 256, 0, stream>>>(row, col, offsBM, part, E, CE);
    bucket_csr_kernel<<<nbk, 256, 0, stream>>>(part, offsBM, csr, offs, dis, N, E, nbk);

    gemm_tile<256><<<(N + 63) / 64, 256, 0, stream>>>(x, W1, dis, xs, N);
    agg_kernel<true, false><<<(N + 15) / 16, 256, 0, stream>>>(xs, csr, offs, dis, b1, h, N);
    gemm_tile<64><<<(N + 63) / 64, 256, 0, stream>>>(h, W2, dis, xs, N);
    agg_kernel<false, true><<<(N + 15) / 16, 256, 0, stream>>>(xs, csr, offs, dis, b2, z, N);
    decode_kernel<<<(L + 15) / 16, 256, 0, stream>>>(z, src, dst, out, L);
}

// Round 12
// 216.124 us; speedup vs baseline: 4.0040x; 1.0406x over previous
//
#include <hip/hip_runtime.h>
#include <hip/hip_bf16.h>

// ---------------------------------------------------------------------------
// GCN: h = relu(gcnconv(x,W1,b1)); z = gcnconv(h,W2,b2); out[e]=dot(z[s],z[d])
// CSR build = bucketed counting sort, 4 kernels: hist(+bucket sums) ->
// rowscan -> reorder -> bucket_csr. part entries packed (row<<8 | col&255).
// gemm1 = bf16 MFMA (16x16x32): A direct from fp32 x (cvt in regs), B from
// pre-packed fragment-layout bf16 W1 (32KB, cache-resident), no LDS/barriers.
// gemm2 stays vector fp32 (small). Epilogues pre-scale by dis, pack bf16.
// Aggregation: one 16-lane group per node, features lane-parallel (no
// reduction), 4-deep unrolled gathers with INDEX PREFETCH (next iteration's
// csr indices load in parallel with current gathers).
// Lessons kept: R9 edge-parallel LDS-atomic agg 7x worse; R5 no __shfl
// across group-divergent tails; R3 block-owned windows for random writes.
// ---------------------------------------------------------------------------

constexpr int NC = 512;      // edge chunks (= hist/reorder grid)
constexpr int NBPAD = 256;   // padded bucket count (>= 196 actual)
constexpr int BSHIFT = 8;    // 256 nodes per bucket

using short8 = __attribute__((ext_vector_type(8))) short;
using f32x4 = __attribute__((ext_vector_type(4))) float;

__device__ __forceinline__ unsigned short f2bf(float f) {   // RNE
    unsigned u = __float_as_uint(f);
    return (unsigned short)((u + 0x7FFF + ((u >> 16) & 1)) >> 16);
}
__device__ __forceinline__ float bf2f(unsigned short h) {
    return __uint_as_float(((unsigned)h) << 16);
}
__device__ __forceinline__ float4 bf4_to_f4(ushort4 u) {
    return make_float4(bf2f(u.x), bf2f(u.y), bf2f(u.z), bf2f(u.w));
}

// histCM[c*NBPAD+b] = bucket-b count in chunk c; bsums[b] = bucket totals.
__global__ __launch_bounds__(256) void hist_kernel(const int* __restrict__ col,
                                                   int* __restrict__ histCM,
                                                   int* __restrict__ bsums, int E, int CE) {
    __shared__ int hl[NBPAD];
    const int t = threadIdx.x, c = blockIdx.x;
    hl[t] = 0;
    __syncthreads();
    const int s = c * CE, e = min(E, s + CE);
    for (int i = s + t; i < e; i += 256) atomicAdd(&hl[col[i] >> BSHIFT], 1);
    __syncthreads();
    const int v = hl[t];
    histCM[c * NBPAD + t] = v;
    if (v) atomicAdd(&bsums[t], v);
}

// Block b: bucket base = sum(bsums[k<b]) (masked reduce), then exclusive scan
// of the bucket's NC chunk counts (2/thread) -> offsBM[b*NC+c].
__global__ __launch_bounds__(256) void rowscan_kernel(const int* __restrict__ histCM,
                                                      const int* __restrict__ bsums,
                                                      int* __restrict__ offsBM) {
    __shared__ int red[256];
    __shared__ int sc[256];
    const int t = threadIdx.x, b = blockIdx.x;
    red[t] = (t < b) ? bsums[t] : 0;
    __syncthreads();
    for (int off = 128; off > 0; off >>= 1) {
        if (t < off) red[t] += red[t + off];
        __syncthreads();
    }
    const int base = red[0];
    const int a0 = histCM[(2 * t) * NBPAD + b];
    const int a1 = histCM[(2 * t + 1) * NBPAD + b];
    const int ps = a0 + a1;
    sc[t] = ps;
    __syncthreads();
    for (int off = 1; off < 256; off <<= 1) {
        int u = (t >= off) ? sc[t - off] : 0;
        __syncthreads();
        sc[t] += u;
        __syncthreads();
    }
    const int excl = sc[t] - ps;
    offsBM[b * NC + 2 * t] = base + excl;
    offsBM[b * NC + 2 * t + 1] = base + excl + a0;
}

// Scatter packed (row<<8 | col&255) into per-(bucket,chunk) runs of part[].
__global__ __launch_bounds__(256) void reorder_kernel(const int* __restrict__ row,
                                                      const int* __restrict__ col,
                                                      const int* __restrict__ offsBM,
                                                      int* __restrict__ part, int E, int CE) {
    __shared__ int cur[NBPAD];
    const int t = threadIdx.x, c = blockIdx.x;
    cur[t] = offsBM[t * NC + c];
    __syncthreads();
    const int s = c * CE, e = min(E, s + CE);
    for (int i = s + t; i < e; i += 256) {
        const int r = row[i], cl = col[i];
        const int p = atomicAdd(&cur[cl >> BSHIFT], 1);
        part[p] = (r << 8) | (cl & 255);   // row < 65536 fits 16 bits
    }
}

// One block per bucket: LDS degree count -> LDS scan -> offs/dis -> scatter
// rows into the bucket's private csr window.
__global__ __launch_bounds__(256) void bucket_csr_kernel(const int* __restrict__ part,
                                                         const int* __restrict__ offsBM,
                                                         int* __restrict__ csr,
                                                         int* __restrict__ offs,
                                                         float* __restrict__ dis,
                                                         int N, int E, int nbk) {
    __shared__ int cnt[256];
    __shared__ int sc[256];
    const int t = threadIdx.x, b = blockIdx.x;
    const int base = b << BSHIFT;
    const int bstart = offsBM[b * NC];
    const int bend = (b + 1 < NBPAD) ? offsBM[(b + 1) * NC] : E;
    const int m = bend - bstart;
    cnt[t] = 0;
    __syncthreads();
    for (int i = t; i < m; i += 256) atomicAdd(&cnt[part[bstart + i] & 255], 1);
    __syncthreads();
    const int v = cnt[t];
    sc[t] = v;
    __syncthreads();
    for (int off = 1; off < 256; off <<= 1) {
        int u = (t >= off) ? sc[t - off] : 0;
        __syncthreads();
        sc[t] += u;
        __syncthreads();
    }
    const int excl = sc[t] - v;
    const int node = base + t;
    if (node < N) {
        offs[node] = bstart + excl;
        dis[node] = rsqrtf((float)(v + 1));   // +1 = self loop
    }
    sc[t] = excl;          // repurpose as scatter cursor
    __syncthreads();
    for (int i = t; i < m; i += 256) {
        const int pc = part[bstart + i];
        const int p = atomicAdd(&sc[pc & 255], 1);
        csr[bstart + p] = pc >> 8;
    }
    if (b == nbk - 1 && t == 0) offs[N] = E;
}

// Pack W[K][64] fp32 -> bf16 in B-fragment layout:
// Wp[((k>>3)*64 + c)*8 + (k&7)] so a lane's 8 k-consecutive elements for a
// fixed column are one 16B load. One 256-thread block.
__global__ __launch_bounds__(256) void pack_w_kernel(const float* __restrict__ W,
                                                     unsigned short* __restrict__ Wp, int K) {
    const int k = threadIdx.x;
    if (k < K) {
        for (int c = 0; c < 64; ++c)
            Wp[((k >> 3) * 64 + c) * 8 + (k & 7)] = f2bf(W[k * 64 + c]);
    }
}

// gemm1 via bf16 MFMA 16x16x32. Block = 4 waves; wave = 16 rows x 64 cols
// (4 ctiles of 16). A: lane m=lane&15, quad=lane>>4, k=ks*32+quad*8+j, loaded
// from fp32 x and cvt'd. B: Wp fragment-layout 16B loads (n=lane&15).
// C/D: col=lane&15, row=quad*4+reg (m89-verified). Epilogue: dis-scale+bf16.
template <int K>
__global__ __launch_bounds__(256) void gemm_mfma(const float* __restrict__ X,
                                                 const unsigned short* __restrict__ Wp,
                                                 const float* __restrict__ rowscale,
                                                 unsigned short* __restrict__ Y, int nrows) {
    const int tid = threadIdx.x;
    const int wv = tid >> 6;
    const int lane = tid & 63;
    const int m = lane & 15;
    const int quad = lane >> 4;
    const int rowbase = blockIdx.x * 64 + wv * 16;

    int grow = rowbase + m;
    if (grow >= nrows) grow = nrows - 1;   // clamp; stores guarded
    const float* xrow = X + (long)grow * K + quad * 8;

    f32x4 acc0 = {0.f, 0.f, 0.f, 0.f};
    f32x4 acc1 = acc0, acc2 = acc0, acc3 = acc0;

    #pragma unroll
    for (int ks = 0; ks < K / 32; ++ks) {
        const float4 a0 = *(const float4*)(xrow + ks * 32);
        const float4 a1 = *(const float4*)(xrow + ks * 32 + 4);
        short8 af;
        af[0] = (short)f2bf(a0.x); af[1] = (short)f2bf(a0.y);
        af[2] = (short)f2bf(a0.z); af[3] = (short)f2bf(a0.w);
        af[4] = (short)f2bf(a1.x); af[5] = (short)f2bf(a1.y);
        af[6] = (short)f2bf(a1.z); af[7] = (short)f2bf(a1.w);
        const unsigned short* bp = Wp + (size_t)((ks * 4 + quad) * 64) * 8;
        const short8 b0 = *(const short8*)(bp + (0 * 16 + m) * 8);
        const short8 b1 = *(const short8*)(bp + (1 * 16 + m) * 8);
        const short8 b2 = *(const short8*)(bp + (2 * 16 + m) * 8);
        const short8 b3 = *(const short8*)(bp + (3 * 16 + m) * 8);
        acc0 = __builtin_amdgcn_mfma_f32_16x16x32_bf16(af, b0, acc0, 0, 0, 0);
        acc1 = __builtin_amdgcn_mfma_f32_16x16x32_bf16(af, b1, acc1, 0, 0, 0);
        acc2 = __builtin_amdgcn_mfma_f32_16x16x32_bf16(af, b2, acc2, 0, 0, 0);
        acc3 = __builtin_amdgcn_mfma_f32_16x16x32_bf16(af, b3, acc3, 0, 0, 0);
    }

    #pragma unroll
    for (int reg = 0; reg < 4; ++reg) {
        const int orow = rowbase + quad * 4 + reg;
        if (orow < nrows) {
            const float d = rowscale[orow];
            unsigned short* yp = Y + (size_t)orow * 64 + m;
            yp[0]  = f2bf(d * acc0[reg]);
            yp[16] = f2bf(d * acc1[reg]);
            yp[32] = f2bf(d * acc2[reg]);
            yp[48] = f2bf(d * acc3[reg]);
        }
    }
}

// Y[N,64] (bf16) = rowscale[r] * (X[N,K] @ W[K,64]) - vector fp32 (gemm2).
template <int K>
__global__ __launch_bounds__(256) void gemm_tile(const float* __restrict__ X,
                                                 const float* __restrict__ W,
                                                 const float* __restrict__ rowscale,
                                                 unsigned short* __restrict__ Y, int nrows) {
    __shared__ float sX[64 * 64];
    __shared__ float sW[64 * 64];
    const int tid = threadIdx.x;
    const int tx = tid & 15;         // col group
    const int ty = tid >> 4;         // row group
    const int rowbase = blockIdx.x * 64;

    float acc[16];
    #pragma unroll
    for (int i = 0; i < 16; ++i) acc[i] = 0.f;

    const int lr = tid & 63;
    const int lq = tid >> 6;
    int grow = rowbase + lr;
    if (grow >= nrows) grow = nrows - 1;
    const float* xrow = X + (long)grow * K;

    for (int kc = 0; kc < K; kc += 64) {
        if (kc) __syncthreads();
        #pragma unroll
        for (int i = 0; i < 4; ++i) {
            const int o = tid * 4 + i * 1024;
            *(float4*)&sW[o] = *(const float4*)&W[(long)kc * 64 + o];
        }
        #pragma unroll
        for (int t = 0; t < 4; ++t) {
            const int k = lq * 16 + t * 4;
            const float4 v = *(const float4*)&xrow[kc + k];
            sX[(k + 0) * 64 + lr] = v.x;
            sX[(k + 1) * 64 + lr] = v.y;
            sX[(k + 2) * 64 + lr] = v.z;
            sX[(k + 3) * 64 + lr] = v.w;
        }
        __syncthreads();
        #pragma unroll 4
        for (int k = 0; k < 64; ++k) {
            const float4 xv = *(const float4*)&sX[k * 64 + ty * 4];
            const float4 wv = *(const float4*)&sW[k * 64 + tx * 4];
            acc[0]  = fmaf(xv.x, wv.x, acc[0]);
            acc[1]  = fmaf(xv.x, wv.y, acc[1]);
            acc[2]  = fmaf(xv.x, wv.z, acc[2]);
            acc[3]  = fmaf(xv.x, wv.w, acc[3]);
            acc[4]  = fmaf(xv.y, wv.x, acc[4]);
            acc[5]  = fmaf(xv.y, wv.y, acc[5]);
            acc[6]  = fmaf(xv.y, wv.z, acc[6]);
            acc[7]  = fmaf(xv.y, wv.w, acc[7]);
            acc[8]  = fmaf(xv.z, wv.x, acc[8]);
            acc[9]  = fmaf(xv.z, wv.y, acc[9]);
            acc[10] = fmaf(xv.z, wv.z, acc[10]);
            acc[11] = fmaf(xv.z, wv.w, acc[11]);
            acc[12] = fmaf(xv.w, wv.x, acc[12]);
            acc[13] = fmaf(xv.w, wv.y, acc[13]);
            acc[14] = fmaf(xv.w, wv.z, acc[14]);
            acc[15] = fmaf(xv.w, wv.w, acc[15]);
        }
    }

    #pragma unroll
    for (int i = 0; i < 4; ++i) {
        const int orow = rowbase + ty * 4 + i;
        if (orow < nrows) {
            const float d = rowscale[orow];
            ushort4 ov;
            ov.x = f2bf(d * acc[i * 4 + 0]);
            ov.y = f2bf(d * acc[i * 4 + 1]);
            ov.z = f2bf(d * acc[i * 4 + 2]);
            ov.w = f2bf(d * acc[i * 4 + 3]);
            *(ushort4*)&Y[(long)orow * 64 + tx * 4] = ov;
        }
    }
}

// One 16-lane group per node; lane fl owns feats fl*4..+3 (8B bf16).
// Features lane-parallel -> no reduction, no LDS. Index PREFETCH: next
// iteration's 4 csr indices load in parallel with current gathers, removing
// the 2-hop (index -> gather) serial latency from the loop-carried chain.
template <bool RELU, bool OUT_BF16>
__global__ __launch_bounds__(256) void agg_kernel(const unsigned short* __restrict__ xs,
                                                  const int* __restrict__ csr,
                                                  const int* __restrict__ offs,
                                                  const float* __restrict__ dis,
                                                  const float* __restrict__ bias,
                                                  void* __restrict__ out, int n) {
    const int t = threadIdx.x;
    const int fl = t & 15;
    const int i = blockIdx.x * 16 + (t >> 4);   // node per 16-lane group
    if (i >= n) return;                          // no barriers below: safe
    float4 acc = bf4_to_f4(*(const ushort4*)&xs[(long)i * 64 + fl * 4]);  // self loop
    const int s = offs[i];
    const int e = offs[i + 1];
    int j = s;
    int r0 = 0, r1 = 0, r2 = 0, r3 = 0;
    if (j + 3 < e) { r0 = csr[j]; r1 = csr[j + 1]; r2 = csr[j + 2]; r3 = csr[j + 3]; }
    while (j + 3 < e) {
        const int jn = j + 4;
        // prefetch next indices (clamped: always in-bounds, unused in tail)
        const int c0 = min(jn,     e - 1), c1 = min(jn + 1, e - 1);
        const int c2 = min(jn + 2, e - 1), c3 = min(jn + 3, e - 1);
        const int n0 = csr[c0], n1 = csr[c1], n2 = csr[c2], n3 = csr[c3];
        const float4 v0 = bf4_to_f4(*(const ushort4*)&xs[(long)r0 * 64 + fl * 4]);
        const float4 v1 = bf4_to_f4(*(const ushort4*)&xs[(long)r1 * 64 + fl * 4]);
        const float4 v2 = bf4_to_f4(*(const ushort4*)&xs[(long)r2 * 64 + fl * 4]);
        const float4 v3 = bf4_to_f4(*(const ushort4*)&xs[(long)r3 * 64 + fl * 4]);
        acc.x += (v0.x + v1.x) + (v2.x + v3.x);
        acc.y += (v0.y + v1.y) + (v2.y + v3.y);
        acc.z += (v0.z + v1.z) + (v2.z + v3.z);
        acc.w += (v0.w + v1.w) + (v2.w + v3.w);
        r0 = n0; r1 = n1; r2 = n2; r3 = n3;
        j = jn;
    }
    for (; j < e; ++j) {
        const int r = csr[j];
        const float4 v = bf4_to_f4(*(const ushort4*)&xs[(long)r * 64 + fl * 4]);
        acc.x += v.x; acc.y += v.y; acc.z += v.z; acc.w += v.w;
    }
    const float di = dis[i];
    const float4 b = *(const float4*)&bias[fl * 4];
    float4 o;
    o.x = fmaf(acc.x, di, b.x); o.y = fmaf(acc.y, di, b.y);
    o.z = fmaf(acc.z, di, b.z); o.w = fmaf(acc.w, di, b.w);
    if (RELU) {
        o.x = fmaxf(o.x, 0.f); o.y = fmaxf(o.y, 0.f);
        o.z = fmaxf(o.z, 0.f); o.w = fmaxf(o.w, 0.f);
    }
    if (OUT_BF16) {
        ushort4 ov;
        ov.x = f2bf(o.x); ov.y = f2bf(o.y); ov.z = f2bf(o.z); ov.w = f2bf(o.w);
        *(ushort4*)&((unsigned short*)out)[(long)i * 64 + fl * 4] = ov;
    } else {
        *(float4*)&((float*)out)[(long)i * 64 + fl * 4] = o;
    }
}

// 16 lanes per label edge: bf16 gathers of z[src], z[dst]; 4-step xor reduce
// (within-group shfl: all 16 source lanes share the group's control flow).
__global__ __launch_bounds__(256) void decode_kernel(const unsigned short* __restrict__ z,
                                                     const int* __restrict__ src,
                                                     const int* __restrict__ dst,
                                                     float* __restrict__ out, int L) {
    const int t = blockIdx.x * 256 + threadIdx.x;
    const int e = t >> 4;
    const int fl = t & 15;
    if (e >= L) return;
    const int s = src[e];
    const int d = dst[e];
    const float4 a = bf4_to_f4(*(const ushort4*)&z[(long)s * 64 + fl * 4]);
    const float4 b = bf4_to_f4(*(const ushort4*)&z[(long)d * 64 + fl * 4]);
    float p = a.x * b.x + a.y * b.y + a.z * b.z + a.w * b.w;
    p += __shfl_xor(p, 8); p += __shfl_xor(p, 4);
    p += __shfl_xor(p, 2); p += __shfl_xor(p, 1);
    if (fl == 0) out[e] = p;
}

extern "C" void kernel_launch(void* const* d_in, const int* in_sizes, int n_in,
                              void* d_out, int out_size, void* d_ws, size_t ws_size,
                              hipStream_t stream) {
    const float* x   = (const float*)d_in[0];
    const int*   ei  = (const int*)d_in[1];
    const int*   eli = (const int*)d_in[2];
    const float* W1  = (const float*)d_in[3];
    const float* b1  = (const float*)d_in[4];
    const float* W2  = (const float*)d_in[5];
    const float* b2  = (const float*)d_in[6];
    float* out = (float*)d_out;

    const int N = in_sizes[0] / 256;   // 50000 nodes (IN_CH = 256)
    const int E = in_sizes[1] / 2;     // 800000 edges
    const int L = in_sizes[2] / 2;     // 200000 label edges
    const int* row = ei;
    const int* col = ei + E;
    const int* src = eli;
    const int* dst = eli + L;

    char* w = (char*)d_ws;
    unsigned short* xs = (unsigned short*)w;  w += (size_t)N * 64 * 2;  // bf16 pre-agg feats
    float* h   = (float*)w;  w += (size_t)N * 64 * 4;                   // layer-1 output (fp32)
    unsigned short* z = (unsigned short*)w;  w += (size_t)N * 64 * 2;   // bf16 layer-2 output
    int*   csr = (int*)w;    w += (size_t)E * 4;          // sources sorted by target
    int*   offs = (int*)w;   w += (size_t)(N + 1) * 4;    // CSR offsets (N+1)
    float* dis = (float*)w;  w += (size_t)N * 4;          // rsqrt(deg+1)
    int*   part = (int*)w;   w += (size_t)E * 4;          // packed (row<<8|col&255)
    int* histCM = (int*)w;   w += (size_t)NC * NBPAD * 4; // per-(chunk,bucket) counts
    int* offsBM = (int*)w;   w += (size_t)NBPAD * NC * 4; // per-(bucket,chunk) offsets
    int* bsums  = (int*)w;   w += NBPAD * 4;              // bucket totals
    unsigned short* Wp1 = (unsigned short*)w;  w += (size_t)256 * 64 * 2;  // packed bf16 W1

    const int CE = (E + NC - 1) / NC;
    const int nbk = (N + (1 << BSHIFT) - 1) >> BSHIFT;    // 196 buckets

    hipMemsetAsync(bsums, 0, NBPAD * sizeof(int), stream);
    pack_w_kernel<<<1, 256, 0, stream>>>(W1, Wp1, 256);
    hist_kernel<<<NC, 256, 0, stream>>>(col, histCM, bsums, E, CE);
    rowscan_kernel<<<NBPAD, 256, 0, stream>>>(histCM, bsums, offsBM);
    reorder_kernel<<<NC, 256, 0, stream>>>(row, col, offsBM, part, E, CE);
    bucket_csr_kernel<<<nbk, 256, 0, stream>>>(part, offsBM, csr, offs, dis, N, E, nbk);

    gemm_mfma<256><<<(N + 63) / 64, 256, 0, stream>>>(x, Wp1, dis, xs, N);
    agg_kernel<true, false><<<(N + 15) / 16, 256, 0, stream>>>(xs, csr, offs, dis, b1, h, N);
    gemm_tile<64><<<(N + 63) / 64, 256, 0, stream>>>(h, W2, dis, xs, N);
    agg_kernel<false, true><<<(N + 15) / 16, 256, 0, stream>>>(xs, csr, offs, dis, b2, z, N);
    decode_kernel<<<(L + 15) / 16, 256, 0, stream>>>(z, src, dst, out, L);
}